// Round 5
// baseline (7333.746 us; speedup 1.0000x reference)
//
#include <hip/hip_runtime.h>
#include <math.h>

#define D_DIM    2048
#define BT_DIM   16384   // B*T
#define NSLOTS   4096
#define NTILES   32      // NSLOTS / 128
#define SCALE    0.02209708691207961f  // 1/sqrt(2048)
#define MARGIN   0.02f
#define CAND_MAX 16
#define KSPLIT   4

typedef __attribute__((ext_vector_type(8))) short bf16x8;
typedef __attribute__((ext_vector_type(4))) float f32x4;
typedef __attribute__((ext_vector_type(8))) unsigned short u16x8;
typedef __attribute__((ext_vector_type(4))) unsigned short u16x4;

__device__ __forceinline__ unsigned short f2bf(float f) {
    unsigned int u = __float_as_uint(f);
    return (unsigned short)((u + 0x7fffu + ((u >> 16) & 1u)) >> 16);
}
__device__ __forceinline__ float bf2f(unsigned short s) {
    return __uint_as_float(((unsigned int)s) << 16);
}

__device__ __forceinline__ void async_cp16(const void* g, void* l) {
    __builtin_amdgcn_global_load_lds(
        (const __attribute__((address_space(1))) void*)g,
        (__attribute__((address_space(3))) void*)l, 16, 0, 0);
}

// ---------------------------------------------------------------------------
// top-4 helpers (jax semantics: val desc, idx asc)
// ---------------------------------------------------------------------------
__device__ __forceinline__ bool cand_better(float v, int i, float v2, int i2) {
    return (v > v2) || (v == v2 && i < i2);
}

__device__ __forceinline__ void cand_insert(float v, int idx,
                                            float& v0, int& i0, float& v1, int& i1,
                                            float& v2, int& i2, float& v3, int& i3) {
    if (cand_better(v, idx, v3, i3)) {
        if (cand_better(v, idx, v0, i0)) {
            v3 = v2; i3 = i2; v2 = v1; i2 = i1; v1 = v0; i1 = i0; v0 = v; i0 = idx;
        } else if (cand_better(v, idx, v1, i1)) {
            v3 = v2; i3 = i2; v2 = v1; i2 = i1; v1 = v; i1 = idx;
        } else if (cand_better(v, idx, v2, i2)) {
            v3 = v2; i3 = i2; v2 = v; i2 = idx;
        } else {
            v3 = v; i3 = idx;
        }
    }
}

// ---------------------------------------------------------------------------
// fp32: Cpart[z] = A[M,Kc] @ B[Kc,N] for K-chunk z (K-split for occupancy).
// KNOWN-GOOD math (rounds 2-3): per-16-step local accumulator feeds the
// exact-refine path -- do not change accumulation order.
// ---------------------------------------------------------------------------
__global__ __launch_bounds__(256)
void gemm_ab_f32_ksplit(const float* __restrict__ A, const float* __restrict__ B,
                        float* __restrict__ Cpart, int M, int N, int K) {
    __shared__ float As[16][128];   // [k][m]
    __shared__ float Bs[16][128];   // [k][n]

    const int tid = threadIdx.x;
    const int bm  = blockIdx.y * 128;
    const int bn  = blockIdx.x * 128;
    const int kc  = K / KSPLIT;
    const int ks  = blockIdx.z * kc;
    float* C = Cpart + (size_t)blockIdx.z * M * N;
    const int ty  = tid >> 4;
    const int tx  = tid & 15;

    float acc[2][2][4][4];
#pragma unroll
    for (int rb = 0; rb < 2; ++rb)
#pragma unroll
        for (int cb = 0; cb < 2; ++cb)
#pragma unroll
            for (int i = 0; i < 4; ++i)
#pragma unroll
                for (int j = 0; j < 4; ++j) acc[rb][cb][i][j] = 0.0f;

    for (int k0 = ks; k0 < ks + kc; k0 += 16) {
#pragma unroll
        for (int half = 0; half < 2; ++half) {
            const int p = tid + half * 256;
            const int rowA = p >> 2;
            const int kkA  = (p & 3) << 2;
            float4 a4 = *(const float4*)(A + (size_t)(bm + rowA) * K + (k0 + kkA));
            As[kkA + 0][rowA] = a4.x;
            As[kkA + 1][rowA] = a4.y;
            As[kkA + 2][rowA] = a4.z;
            As[kkA + 3][rowA] = a4.w;
            const int kB = p >> 5;
            const int n4 = (p & 31) << 2;
            float4 b4 = *(const float4*)(B + (size_t)(k0 + kB) * N + (bn + n4));
            *(float4*)&Bs[kB][n4] = b4;
        }
        __syncthreads();

        float lacc[2][2][4][4];
#pragma unroll
        for (int rb = 0; rb < 2; ++rb)
#pragma unroll
            for (int cb = 0; cb < 2; ++cb)
#pragma unroll
                for (int i = 0; i < 4; ++i)
#pragma unroll
                    for (int j = 0; j < 4; ++j) lacc[rb][cb][i][j] = 0.0f;

#pragma unroll
        for (int k = 0; k < 16; ++k) {
            float a[2][4], b[2][4];
#pragma unroll
            for (int h = 0; h < 2; ++h) {
                *(float4*)a[h] = *(const float4*)&As[k][h * 64 + ty * 4];
                *(float4*)b[h] = *(const float4*)&Bs[k][h * 64 + tx * 4];
            }
#pragma unroll
            for (int rb = 0; rb < 2; ++rb)
#pragma unroll
                for (int cb = 0; cb < 2; ++cb)
#pragma unroll
                    for (int i = 0; i < 4; ++i)
#pragma unroll
                        for (int j = 0; j < 4; ++j)
                            lacc[rb][cb][i][j] =
                                fmaf(a[rb][i], b[cb][j], lacc[rb][cb][i][j]);
        }
#pragma unroll
        for (int rb = 0; rb < 2; ++rb)
#pragma unroll
            for (int cb = 0; cb < 2; ++cb)
#pragma unroll
                for (int i = 0; i < 4; ++i)
#pragma unroll
                    for (int j = 0; j < 4; ++j)
                        acc[rb][cb][i][j] += lacc[rb][cb][i][j];
        __syncthreads();
    }

#pragma unroll
    for (int rb = 0; rb < 2; ++rb)
#pragma unroll
        for (int i = 0; i < 4; ++i) {
            const size_t r = (size_t)(bm + rb * 64 + ty * 4 + i);
#pragma unroll
            for (int cb = 0; cb < 2; ++cb) {
                float4 o;
                o.x = acc[rb][cb][i][0];
                o.y = acc[rb][cb][i][1];
                o.z = acc[rb][cb][i][2];
                o.w = acc[rb][cb][i][3];
                *(float4*)(C + r * N + (bn + cb * 64 + tx * 4)) = o;
            }
        }
}

// ---------------------------------------------------------------------------
// KW = sum of 4 K-chunk partials (deterministic); also emit kwb = bf16(KW).
// ---------------------------------------------------------------------------
__global__ __launch_bounds__(256)
void reduce_kw(const float* __restrict__ part, float* __restrict__ KW,
               unsigned short* __restrict__ kwb) {
    const size_t i = ((size_t)blockIdx.x * 256 + threadIdx.x) * 4;
    const size_t stride = (size_t)NSLOTS * D_DIM;
    float4 s0 = *(const float4*)(part + i);
    float4 s1 = *(const float4*)(part + i + stride);
    float4 s2 = *(const float4*)(part + i + 2 * stride);
    float4 s3 = *(const float4*)(part + i + 3 * stride);
    float4 o;
    o.x = (s0.x + s1.x) + (s2.x + s3.x);
    o.y = (s0.y + s1.y) + (s2.y + s3.y);
    o.z = (s0.z + s1.z) + (s2.z + s3.z);
    o.w = (s0.w + s1.w) + (s2.w + s3.w);
    *(float4*)(KW + i) = o;
    u16x4 b;
    b[0] = f2bf(o.x); b[1] = f2bf(o.y); b[2] = f2bf(o.z); b[3] = f2bf(o.w);
    *(u16x4*)(kwb + i) = b;
}

// ---------------------------------------------------------------------------
// fp32 -> bf16 elementwise (8 elems/thread), exact grid
// ---------------------------------------------------------------------------
__global__ __launch_bounds__(256)
void cvt_f32_bf16(const float* __restrict__ in, unsigned short* __restrict__ out) {
    const size_t i = ((size_t)blockIdx.x * 256 + threadIdx.x) * 8;
    float4 a = *(const float4*)(in + i);
    float4 b = *(const float4*)(in + i + 4);
    u16x8 o;
    o[0] = f2bf(a.x); o[1] = f2bf(a.y); o[2] = f2bf(a.z); o[3] = f2bf(a.w);
    o[4] = f2bf(b.x); o[5] = f2bf(b.y); o[6] = f2bf(b.z); o[7] = f2bf(b.w);
    *(u16x8*)(out + i) = o;
}

// ---------------------------------------------------------------------------
// bf16 MFMA GEMM (out-projection): C[M,N] = A[M,K] @ B[N,K]^T, fp32 out.
// m97 structure: 128x128 tile, BK=32, 4 waves, global_load_lds w=16,
// XOR-swizzle via pre-swizzled global source (linear LDS dest).
// ---------------------------------------------------------------------------
__global__ __launch_bounds__(256)
void gemm_bf16_abt(const unsigned short* __restrict__ A,
                   const unsigned short* __restrict__ B,
                   float* __restrict__ C, int M, int N, int K) {
    __shared__ __align__(16) unsigned short Alds[128 * 32];
    __shared__ __align__(16) unsigned short Blds[128 * 32];

    const int tid  = threadIdx.x;
    const int lane = tid & 63;
    const int w    = tid >> 6;
    const int wr   = w >> 1, wc = w & 1;
    const int bm   = blockIdx.y * 128;
    const int bn   = blockIdx.x * 128;

    const int srow = lane >> 2;
    const int skch = (lane & 3) ^ ((lane >> 3) & 3);
    const int c0 = w, c1 = w + 4;
    const unsigned short* gA0 = A + (size_t)(bm + c0 * 16 + srow) * K + skch * 8;
    const unsigned short* gA1 = A + (size_t)(bm + c1 * 16 + srow) * K + skch * 8;
    const unsigned short* gB0 = B + (size_t)(bn + c0 * 16 + srow) * K + skch * 8;
    const unsigned short* gB1 = B + (size_t)(bn + c1 * 16 + srow) * K + skch * 8;
    char* lA0 = (char*)Alds + c0 * 1024;
    char* lA1 = (char*)Alds + c1 * 1024;
    char* lB0 = (char*)Blds + c0 * 1024;
    char* lB1 = (char*)Blds + c1 * 1024;

    const int kbyte = (((lane >> 4) ^ ((lane >> 1) & 3)) << 4);
    const int rA = wr * 64 + (lane & 15);
    const int rB = wc * 64 + (lane & 15);

    f32x4 acc[4][4] = {};

    for (int kt = 0; kt < K; kt += 32) {
        async_cp16(gA0, lA0);
        async_cp16(gA1, lA1);
        async_cp16(gB0, lB0);
        async_cp16(gB1, lB1);
        gA0 += 32; gA1 += 32; gB0 += 32; gB1 += 32;
        __syncthreads();

        bf16x8 a[4], b[4];
#pragma unroll
        for (int i = 0; i < 4; ++i) {
            a[i] = *(const bf16x8*)((const char*)Alds + (rA + i * 16) * 64 + kbyte);
            b[i] = *(const bf16x8*)((const char*)Blds + (rB + i * 16) * 64 + kbyte);
        }
#pragma unroll
        for (int i = 0; i < 4; ++i)
#pragma unroll
            for (int j = 0; j < 4; ++j)
                acc[i][j] = __builtin_amdgcn_mfma_f32_16x16x32_bf16(
                    a[i], b[j], acc[i][j], 0, 0, 0);
        __syncthreads();
    }

    const int orow = (lane >> 4) * 4;
    const int ocol = lane & 15;
#pragma unroll
    for (int i = 0; i < 4; ++i)
#pragma unroll
        for (int j = 0; j < 4; ++j) {
            const size_t base =
                (size_t)(bm + wr * 64 + i * 16 + orow) * N + (bn + wc * 64 + j * 16 + ocol);
#pragma unroll
            for (int r = 0; r < 4; ++r)
                C[base + (size_t)r * N] = acc[i][j][r];
        }
}

// ---------------------------------------------------------------------------
// Scores GEMM + fused per-tile top-4 epilogue.
// C[M,N] = A[M,K] @ B[N,K]^T (bf16 MFMA); writes scoresb (bf16, fallback
// only) and aux[row][tile][4] = top-4 (f32 val, idx) of this 128-col tile.
// ---------------------------------------------------------------------------
__global__ __launch_bounds__(256)
void gemm_scores_aux(const unsigned short* __restrict__ A,
                     const unsigned short* __restrict__ B,
                     unsigned short* __restrict__ Cb,
                     float4* __restrict__ aux, int M, int N, int K) {
    __shared__ __align__(16) unsigned short Alds[128 * 32];
    __shared__ __align__(16) unsigned short Blds[128 * 32];
    __shared__ float2 mrg[128][9];   // [row][wc*4+e], padded stride vs bank conflicts

    const int tid  = threadIdx.x;
    const int lane = tid & 63;
    const int w    = tid >> 6;
    const int wr   = w >> 1, wc = w & 1;
    const int bm   = blockIdx.y * 128;
    const int bn   = blockIdx.x * 128;

    const int srow = lane >> 2;
    const int skch = (lane & 3) ^ ((lane >> 3) & 3);
    const int c0 = w, c1 = w + 4;
    const unsigned short* gA0 = A + (size_t)(bm + c0 * 16 + srow) * K + skch * 8;
    const unsigned short* gA1 = A + (size_t)(bm + c1 * 16 + srow) * K + skch * 8;
    const unsigned short* gB0 = B + (size_t)(bn + c0 * 16 + srow) * K + skch * 8;
    const unsigned short* gB1 = B + (size_t)(bn + c1 * 16 + srow) * K + skch * 8;
    char* lA0 = (char*)Alds + c0 * 1024;
    char* lA1 = (char*)Alds + c1 * 1024;
    char* lB0 = (char*)Blds + c0 * 1024;
    char* lB1 = (char*)Blds + c1 * 1024;

    const int kbyte = (((lane >> 4) ^ ((lane >> 1) & 3)) << 4);
    const int rA = wr * 64 + (lane & 15);
    const int rB = wc * 64 + (lane & 15);

    f32x4 acc[4][4] = {};

    for (int kt = 0; kt < K; kt += 32) {
        async_cp16(gA0, lA0);
        async_cp16(gA1, lA1);
        async_cp16(gB0, lB0);
        async_cp16(gB1, lB1);
        gA0 += 32; gA1 += 32; gB0 += 32; gB1 += 32;
        __syncthreads();

        bf16x8 a[4], b[4];
#pragma unroll
        for (int i = 0; i < 4; ++i) {
            a[i] = *(const bf16x8*)((const char*)Alds + (rA + i * 16) * 64 + kbyte);
            b[i] = *(const bf16x8*)((const char*)Blds + (rB + i * 16) * 64 + kbyte);
        }
#pragma unroll
        for (int i = 0; i < 4; ++i)
#pragma unroll
            for (int j = 0; j < 4; ++j)
                acc[i][j] = __builtin_amdgcn_mfma_f32_16x16x32_bf16(
                    a[i], b[j], acc[i][j], 0, 0, 0);
        __syncthreads();
    }

    // ---- store bf16 scores (fallback data)
    const int orow = (lane >> 4) * 4;
    const int ocol = lane & 15;
#pragma unroll
    for (int i = 0; i < 4; ++i)
#pragma unroll
        for (int j = 0; j < 4; ++j) {
            const size_t base =
                (size_t)(bm + wr * 64 + i * 16 + orow) * N + (bn + wc * 64 + j * 16 + ocol);
#pragma unroll
            for (int r = 0; r < 4; ++r)
                Cb[base + (size_t)r * N] = f2bf(acc[i][j][r]);
        }

    // ---- epilogue: per-row top-4 within this wave's 64 cols
    const int colbase = bn + wc * 64 + (lane & 15);
    const int g = lane >> 4;
#pragma unroll
    for (int i = 0; i < 4; ++i) {
#pragma unroll
        for (int r = 0; r < 4; ++r) {
            float v0 = -INFINITY, v1 = -INFINITY, v2 = -INFINITY, v3 = -INFINITY;
            int   i0 = 0x7fffffff, i1 = 0x7fffffff, i2 = 0x7fffffff, i3 = 0x7fffffff;
#pragma unroll
            for (int j = 0; j < 4; ++j)
                cand_insert(acc[i][j][r], colbase + j * 16,
                            v0, i0, v1, i1, v2, i2, v3, i3);
            // butterfly over the 16 lanes sharing this row (low 4 lane bits)
#pragma unroll
            for (int off = 1; off < 16; off <<= 1) {
                float s0 = __shfl_xor(v0, off), s1 = __shfl_xor(v1, off);
                float s2 = __shfl_xor(v2, off), s3 = __shfl_xor(v3, off);
                int   t0 = __shfl_xor(i0, off), t1 = __shfl_xor(i1, off);
                int   t2 = __shfl_xor(i2, off), t3 = __shfl_xor(i3, off);
                cand_insert(s0, t0, v0, i0, v1, i1, v2, i2, v3, i3);
                cand_insert(s1, t1, v0, i0, v1, i1, v2, i2, v3, i3);
                cand_insert(s2, t2, v0, i0, v1, i1, v2, i2, v3, i3);
                cand_insert(s3, t3, v0, i0, v1, i1, v2, i2, v3, i3);
            }
            if ((lane & 15) == 0) {
                // FIX (round-4 crash): include wr*64 -- rows 64..127 were
                // unwritten, merge read uninitialized LDS -> garbage slot ids
                // -> OOB KW reads -> device abort.
                const int row = wr * 64 + i * 16 + g * 4 + r;
                mrg[row][wc * 4 + 0] = make_float2(v0, __int_as_float(i0));
                mrg[row][wc * 4 + 1] = make_float2(v1, __int_as_float(i1));
                mrg[row][wc * 4 + 2] = make_float2(v2, __int_as_float(i2));
                mrg[row][wc * 4 + 3] = make_float2(v3, __int_as_float(i3));
            }
        }
    }
    __syncthreads();

    // ---- merge the two 64-col halves, write aux
    if (tid < 128) {
        float v0 = -INFINITY, v1 = -INFINITY, v2 = -INFINITY, v3 = -INFINITY;
        int   i0 = 0x7fffffff, i1 = 0x7fffffff, i2 = 0x7fffffff, i3 = 0x7fffffff;
#pragma unroll
        for (int e = 0; e < 8; ++e) {
            float2 p = mrg[tid][e];
            cand_insert(p.x, __float_as_int(p.y), v0, i0, v1, i1, v2, i2, v3, i3);
        }
        float4 o1, o2;
        o1.x = v0; o1.y = __int_as_float(i0); o1.z = v1; o1.w = __int_as_float(i1);
        o2.x = v2; o2.y = __int_as_float(i2); o2.z = v3; o2.w = __int_as_float(i3);
        float4* dst = aux + ((size_t)(bm + tid) * NTILES + blockIdx.x) * 2;
        dst[0] = o1;
        dst[1] = o2;
    }
}

// ---------------------------------------------------------------------------
// Wave-per-row refine: merge aux (32 tiles x top-4) -> thresh -> candidates
// from aux (non-flagged tiles) + stored-score scan (flagged tiles, rare)
// -> EXACT fp32 re-score (identical math to rounds 2-3) -> softmax -> gather.
// ---------------------------------------------------------------------------
__global__ __launch_bounds__(256)
void topk_refine(const float4* __restrict__ aux,
                 const unsigned short* __restrict__ scoresb,
                 const float* __restrict__ x,
                 const float* __restrict__ KW,
                 const unsigned short* __restrict__ svb,
                 unsigned short* __restrict__ retr) {
    const int tid  = threadIdx.x;
    const int lane = tid & 63;
    const int w    = tid >> 6;
    const int t    = blockIdx.x * 4 + w;

    // x row into registers early (independent of everything below)
    const float* xrow = x + (size_t)t * D_DIM + lane * 4;
    float4 xv[8];
#pragma unroll
    for (int i = 0; i < 8; ++i) xv[i] = *(const float4*)(xrow + 256 * i);

    __shared__ int          cand[4][CAND_MAX];
    __shared__ int          ncand[4];
    __shared__ unsigned int flags[4];
    if (lane == 0) { ncand[w] = 0; flags[w] = 0; }
    __syncthreads();

    // --- merge 128 aux entries (lane holds 2: one float4)
    const float4 e2 = aux[(size_t)t * 64 + lane];
    float v0 = -INFINITY, v1 = -INFINITY, v2 = -INFINITY, v3 = -INFINITY;
    int   i0 = 0x7fffffff, i1 = 0x7fffffff, i2 = 0x7fffffff, i3 = 0x7fffffff;
    cand_insert(e2.x, __float_as_int(e2.y), v0, i0, v1, i1, v2, i2, v3, i3);
    cand_insert(e2.z, __float_as_int(e2.w), v0, i0, v1, i1, v2, i2, v3, i3);
#pragma unroll
    for (int off = 1; off < 64; off <<= 1) {
        float s0 = __shfl_xor(v0, off), s1 = __shfl_xor(v1, off);
        float s2 = __shfl_xor(v2, off), s3 = __shfl_xor(v3, off);
        int   j0 = __shfl_xor(i0, off), j1 = __shfl_xor(i1, off);
        int   j2 = __shfl_xor(i2, off), j3 = __shfl_xor(i3, off);
        cand_insert(s0, j0, v0, i0, v1, i1, v2, i2, v3, i3);
        cand_insert(s1, j1, v0, i0, v1, i1, v2, i2, v3, i3);
        cand_insert(s2, j2, v0, i0, v1, i1, v2, i2, v3, i3);
        cand_insert(s3, j3, v0, i0, v1, i1, v2, i2, v3, i3);
    }
    const float thresh = v3 - MARGIN;

    // --- flag tiles whose 4th entry >= thresh (could hide candidates)
    // odd lane holds entries {2,3} of tile lane>>1; e2.z is the tile's 4th val
    if ((lane & 1) && e2.z >= thresh)
        atomicOr(&flags[w], 1u << (lane >> 1));
    __syncthreads();
    const unsigned int fl = flags[w];

    // --- collect candidates from aux (non-flagged tiles only)
    const int mytile = lane >> 1;
    if (!((fl >> mytile) & 1u)) {
        if (e2.x >= thresh) {
            int p = atomicAdd(&ncand[w], 1);
            if (p < CAND_MAX) cand[w][p] = __float_as_int(e2.y);
        }
        if (e2.z >= thresh) {
            int p = atomicAdd(&ncand[w], 1);
            if (p < CAND_MAX) cand[w][p] = __float_as_int(e2.w);
        }
    }
    // --- flagged tiles: scan stored bf16 scores (rare)
    unsigned int fscan = fl;
    while (fscan) {
        const int tb = __ffs(fscan) - 1;
        fscan &= fscan - 1;
        const unsigned short* srow =
            scoresb + (size_t)t * NSLOTS + tb * 128 + lane * 2;
        const unsigned short s0 = srow[0], s1 = srow[1];
        if (bf2f(s0) >= thresh) {
            int p = atomicAdd(&ncand[w], 1);
            if (p < CAND_MAX) cand[w][p] = tb * 128 + lane * 2;
        }
        if (bf2f(s1) >= thresh) {
            int p = atomicAdd(&ncand[w], 1);
            if (p < CAND_MAX) cand[w][p] = tb * 128 + lane * 2 + 1;
        }
    }
    __syncthreads();
    const int nc = min(ncand[w], CAND_MAX);

    // --- exact fp32 re-score (IDENTICAL math to round-3 validated path)
    float r0 = -INFINITY, r1 = -INFINITY, r2 = -INFINITY, r3 = -INFINITY;
    int   q0 = 0x7fffffff, q1 = 0x7fffffff, q2 = 0x7fffffff, q3 = 0x7fffffff;
    for (int c = 0; c < nc; ++c) {
        const int slot = cand[w][c];
        const float* kr = KW + (size_t)slot * D_DIM + lane * 4;
        float p = 0.0f;
#pragma unroll
        for (int i = 0; i < 8; ++i) {
            const float4 k4 = *(const float4*)(kr + 256 * i);
            p = fmaf(xv[i].x, k4.x, p);
            p = fmaf(xv[i].y, k4.y, p);
            p = fmaf(xv[i].z, k4.z, p);
            p = fmaf(xv[i].w, k4.w, p);
        }
#pragma unroll
        for (int off = 1; off < 64; off <<= 1) p += __shfl_xor(p, off);
        cand_insert(p, slot, r0, q0, r1, q1, r2, q2, r3, q3);
    }

    // --- softmax over scaled top-4 (r0 is max)
    const float e1s = expf(SCALE * (r1 - r0));
    const float e2s = expf(SCALE * (r2 - r0));
    const float e3s = expf(SCALE * (r3 - r0));
    const float inv = 1.0f / (1.0f + e1s + e2s + e3s);
    const float w0s = inv, w1s = e1s * inv, w2s = e2s * inv, w3s = e3s * inv;

    // --- gather bf16 SV rows, weighted sum, write retr (bf16)
    const unsigned short* p0 = svb + (size_t)q0 * D_DIM;
    const unsigned short* p1 = svb + (size_t)q1 * D_DIM;
    const unsigned short* p2 = svb + (size_t)q2 * D_DIM;
    const unsigned short* p3 = svb + (size_t)q3 * D_DIM;
    unsigned short* orow = retr + (size_t)t * D_DIM;
#pragma unroll
    for (int i = 0; i < 4; ++i) {
        const int d0 = lane * 8 + 512 * i;
        u16x8 a0 = *(const u16x8*)(p0 + d0);
        u16x8 a1 = *(const u16x8*)(p1 + d0);
        u16x8 a2 = *(const u16x8*)(p2 + d0);
        u16x8 a3 = *(const u16x8*)(p3 + d0);
        u16x8 o;
#pragma unroll
        for (int e = 0; e < 8; ++e) {
            float s = w0s * bf2f(a0[e]) + w1s * bf2f(a1[e]) +
                      w2s * bf2f(a2[e]) + w3s * bf2f(a3[e]);
            o[e] = f2bf(s);
        }
        *(u16x8*)(orow + d0) = o;
    }
}

// ---------------------------------------------------------------------------
extern "C" void kernel_launch(void* const* d_in, const int* in_sizes, int n_in,
                              void* d_out, int out_size, void* d_ws, size_t ws_size,
                              hipStream_t stream) {
    const float* x    = (const float*)d_in[0];
    const float* sk   = (const float*)d_in[1];
    const float* sv   = (const float*)d_in[2];
    const float* wq   = (const float*)d_in[3];
    const float* wout = (const float*)d_in[4];

    // workspace layout (293.6 MB; proven ws >= 402 MB)
    char* base = (char*)d_ws;
    float*          kwpart  = (float*)base;                       // 4 x 33.55 MB (then reused)
    unsigned short* scoresb = (unsigned short*)base;              // 134.2 MB (after reduce)
    float*          KW      = (float*)(base + 134217728);         //  33.55 MB
    unsigned short* kwb     = (unsigned short*)(base + 167772160);//  16.78 MB
    unsigned short* woutb   = (unsigned short*)(base + 184549376);//   8.39 MB
    unsigned short* xb      = (unsigned short*)(base + 192937984);//  67.11 MB (reused as retr)
    unsigned short* svb     = (unsigned short*)(base + 260046848);//  16.78 MB
    float4*         aux     = (float4*)(base + 276824064);        //  16.78 MB

    const dim3 blk(256);

    // KW partials: SK @ Wq, K split 4 ways
    gemm_ab_f32_ksplit<<<dim3(D_DIM / 128, NSLOTS / 128, KSPLIT), blk, 0, stream>>>(
        sk, wq, kwpart, NSLOTS, D_DIM, D_DIM);

    // KW = sum(partials); kwb = bf16(KW)
    reduce_kw<<<dim3((NSLOTS * (size_t)D_DIM) / 1024), blk, 0, stream>>>(
        kwpart, KW, kwb);

    // bf16 copies
    cvt_f32_bf16<<<dim3((BT_DIM * (size_t)D_DIM) / 2048), blk, 0, stream>>>(x, xb);
    cvt_f32_bf16<<<dim3((D_DIM * (size_t)D_DIM) / 2048), blk, 0, stream>>>(wout, woutb);
    cvt_f32_bf16<<<dim3((NSLOTS * (size_t)D_DIM) / 2048), blk, 0, stream>>>(sv, svb);

    // approx scores + fused per-tile top-4 aux  [overwrites kwpart region]
    gemm_scores_aux<<<dim3(NSLOTS / 128, BT_DIM / 128), blk, 0, stream>>>(
        xb, kwb, scoresb, aux, BT_DIM, NSLOTS, D_DIM);

    // exact top-4 via aux + margin-refine; writes retrieved (bf16) over xb
    topk_refine<<<dim3(BT_DIM / 4), blk, 0, stream>>>(
        aux, scoresb, x, KW, svb, xb);

    // out = retrieved @ Wout^T  (fp32 out)
    gemm_bf16_abt<<<dim3(D_DIM / 128, BT_DIM / 128), blk, 0, stream>>>(
        xb, woutb, (float*)d_out, BT_DIM, D_DIM, D_DIM);
}

// Round 6
// 2595.873 us; speedup vs baseline: 2.8252x; 2.8252x over previous
//
#include <hip/hip_runtime.h>
#include <math.h>

#define D_DIM    2048
#define BT_DIM   16384   // B*T
#define NSLOTS   4096
#define NTILES   32      // NSLOTS / 128
#define SCALE    0.02209708691207961f  // 1/sqrt(2048)
#define MARGIN   0.02f
#define CAND_MAX 16
#define KSPLIT   4

typedef __attribute__((ext_vector_type(8))) short bf16x8;
typedef __attribute__((ext_vector_type(4))) float f32x4;
typedef __attribute__((ext_vector_type(8))) unsigned short u16x8;
typedef __attribute__((ext_vector_type(4))) unsigned short u16x4;

__device__ __forceinline__ unsigned short f2bf(float f) {
    unsigned int u = __float_as_uint(f);
    return (unsigned short)((u + 0x7fffu + ((u >> 16) & 1u)) >> 16);
}
__device__ __forceinline__ float bf2f(unsigned short s) {
    return __uint_as_float(((unsigned int)s) << 16);
}

__device__ __forceinline__ void async_cp16(const void* g, void* l) {
    __builtin_amdgcn_global_load_lds(
        (const __attribute__((address_space(1))) void*)g,
        (__attribute__((address_space(3))) void*)l, 16, 0, 0);
}

// ---------------------------------------------------------------------------
// top-4 helpers (jax semantics: val desc, idx asc)
// ---------------------------------------------------------------------------
__device__ __forceinline__ bool cand_better(float v, int i, float v2, int i2) {
    return (v > v2) || (v == v2 && i < i2);
}

__device__ __forceinline__ void cand_insert(float v, int idx,
                                            float& v0, int& i0, float& v1, int& i1,
                                            float& v2, int& i2, float& v3, int& i3) {
    if (cand_better(v, idx, v3, i3)) {
        if (cand_better(v, idx, v0, i0)) {
            v3 = v2; i3 = i2; v2 = v1; i2 = i1; v1 = v0; i1 = i0; v0 = v; i0 = idx;
        } else if (cand_better(v, idx, v1, i1)) {
            v3 = v2; i3 = i2; v2 = v1; i2 = i1; v1 = v; i1 = idx;
        } else if (cand_better(v, idx, v2, i2)) {
            v3 = v2; i3 = i2; v2 = v; i2 = idx;
        } else {
            v3 = v; i3 = idx;
        }
    }
}

// ---------------------------------------------------------------------------
// fp32: Cpart[z] = A[M,Kc] @ B[Kc,N] for K-chunk z (K-split for occupancy).
// KNOWN-GOOD math (rounds 2-5): per-16-step local accumulator feeds the
// exact-refine path -- do not change accumulation order.
// ---------------------------------------------------------------------------
__global__ __launch_bounds__(256)
void gemm_ab_f32_ksplit(const float* __restrict__ A, const float* __restrict__ B,
                        float* __restrict__ Cpart, int M, int N, int K) {
    __shared__ float As[16][128];   // [k][m]
    __shared__ float Bs[16][128];   // [k][n]

    const int tid = threadIdx.x;
    const int bm  = blockIdx.y * 128;
    const int bn  = blockIdx.x * 128;
    const int kc  = K / KSPLIT;
    const int ks  = blockIdx.z * kc;
    float* C = Cpart + (size_t)blockIdx.z * M * N;
    const int ty  = tid >> 4;
    const int tx  = tid & 15;

    float acc[2][2][4][4];
#pragma unroll
    for (int rb = 0; rb < 2; ++rb)
#pragma unroll
        for (int cb = 0; cb < 2; ++cb)
#pragma unroll
            for (int i = 0; i < 4; ++i)
#pragma unroll
                for (int j = 0; j < 4; ++j) acc[rb][cb][i][j] = 0.0f;

    for (int k0 = ks; k0 < ks + kc; k0 += 16) {
#pragma unroll
        for (int half = 0; half < 2; ++half) {
            const int p = tid + half * 256;
            const int rowA = p >> 2;
            const int kkA  = (p & 3) << 2;
            float4 a4 = *(const float4*)(A + (size_t)(bm + rowA) * K + (k0 + kkA));
            As[kkA + 0][rowA] = a4.x;
            As[kkA + 1][rowA] = a4.y;
            As[kkA + 2][rowA] = a4.z;
            As[kkA + 3][rowA] = a4.w;
            const int kB = p >> 5;
            const int n4 = (p & 31) << 2;
            float4 b4 = *(const float4*)(B + (size_t)(k0 + kB) * N + (bn + n4));
            *(float4*)&Bs[kB][n4] = b4;
        }
        __syncthreads();

        float lacc[2][2][4][4];
#pragma unroll
        for (int rb = 0; rb < 2; ++rb)
#pragma unroll
            for (int cb = 0; cb < 2; ++cb)
#pragma unroll
                for (int i = 0; i < 4; ++i)
#pragma unroll
                    for (int j = 0; j < 4; ++j) lacc[rb][cb][i][j] = 0.0f;

#pragma unroll
        for (int k = 0; k < 16; ++k) {
            float a[2][4], b[2][4];
#pragma unroll
            for (int h = 0; h < 2; ++h) {
                *(float4*)a[h] = *(const float4*)&As[k][h * 64 + ty * 4];
                *(float4*)b[h] = *(const float4*)&Bs[k][h * 64 + tx * 4];
            }
#pragma unroll
            for (int rb = 0; rb < 2; ++rb)
#pragma unroll
                for (int cb = 0; cb < 2; ++cb)
#pragma unroll
                    for (int i = 0; i < 4; ++i)
#pragma unroll
                        for (int j = 0; j < 4; ++j)
                            lacc[rb][cb][i][j] =
                                fmaf(a[rb][i], b[cb][j], lacc[rb][cb][i][j]);
        }
#pragma unroll
        for (int rb = 0; rb < 2; ++rb)
#pragma unroll
            for (int cb = 0; cb < 2; ++cb)
#pragma unroll
                for (int i = 0; i < 4; ++i)
#pragma unroll
                    for (int j = 0; j < 4; ++j)
                        acc[rb][cb][i][j] += lacc[rb][cb][i][j];
        __syncthreads();
    }

#pragma unroll
    for (int rb = 0; rb < 2; ++rb)
#pragma unroll
        for (int i = 0; i < 4; ++i) {
            const size_t r = (size_t)(bm + rb * 64 + ty * 4 + i);
#pragma unroll
            for (int cb = 0; cb < 2; ++cb) {
                float4 o;
                o.x = acc[rb][cb][i][0];
                o.y = acc[rb][cb][i][1];
                o.z = acc[rb][cb][i][2];
                o.w = acc[rb][cb][i][3];
                *(float4*)(C + r * N + (bn + cb * 64 + tx * 4)) = o;
            }
        }
}

// ---------------------------------------------------------------------------
// KW = sum of 4 K-chunk partials (deterministic); also emit kwb = bf16(KW).
// ---------------------------------------------------------------------------
__global__ __launch_bounds__(256)
void reduce_kw(const float* __restrict__ part, float* __restrict__ KW,
               unsigned short* __restrict__ kwb) {
    const size_t i = ((size_t)blockIdx.x * 256 + threadIdx.x) * 4;
    const size_t stride = (size_t)NSLOTS * D_DIM;
    float4 s0 = *(const float4*)(part + i);
    float4 s1 = *(const float4*)(part + i + stride);
    float4 s2 = *(const float4*)(part + i + 2 * stride);
    float4 s3 = *(const float4*)(part + i + 3 * stride);
    float4 o;
    o.x = (s0.x + s1.x) + (s2.x + s3.x);
    o.y = (s0.y + s1.y) + (s2.y + s3.y);
    o.z = (s0.z + s1.z) + (s2.z + s3.z);
    o.w = (s0.w + s1.w) + (s2.w + s3.w);
    *(float4*)(KW + i) = o;
    u16x4 b;
    b[0] = f2bf(o.x); b[1] = f2bf(o.y); b[2] = f2bf(o.z); b[3] = f2bf(o.w);
    *(u16x4*)(kwb + i) = b;
}

// ---------------------------------------------------------------------------
// fp32 -> bf16 elementwise (8 elems/thread), exact grid
// ---------------------------------------------------------------------------
__global__ __launch_bounds__(256)
void cvt_f32_bf16(const float* __restrict__ in, unsigned short* __restrict__ out) {
    const size_t i = ((size_t)blockIdx.x * 256 + threadIdx.x) * 8;
    float4 a = *(const float4*)(in + i);
    float4 b = *(const float4*)(in + i + 4);
    u16x8 o;
    o[0] = f2bf(a.x); o[1] = f2bf(a.y); o[2] = f2bf(a.z); o[3] = f2bf(a.w);
    o[4] = f2bf(b.x); o[5] = f2bf(b.y); o[6] = f2bf(b.z); o[7] = f2bf(b.w);
    *(u16x8*)(out + i) = o;
}

// ---------------------------------------------------------------------------
// bf16 MFMA GEMM: C[M,N] = A[M,K] @ B[N,K]^T; C fp32 or bf16 (template).
// m97 structure, PURE (no epilogue fusion -- round-5 lesson: the tournament
// epilogue spilled the accumulator to scratch, 30 GB traffic).
// ---------------------------------------------------------------------------
template <bool BF16_OUT>
__global__ __launch_bounds__(256)
void gemm_bf16_abt(const unsigned short* __restrict__ A,
                   const unsigned short* __restrict__ B,
                   void* __restrict__ Cv, int M, int N, int K) {
    __shared__ __align__(16) unsigned short Alds[128 * 32];
    __shared__ __align__(16) unsigned short Blds[128 * 32];

    const int tid  = threadIdx.x;
    const int lane = tid & 63;
    const int w    = tid >> 6;
    const int wr   = w >> 1, wc = w & 1;
    const int bm   = blockIdx.y * 128;
    const int bn   = blockIdx.x * 128;

    const int srow = lane >> 2;
    const int skch = (lane & 3) ^ ((lane >> 3) & 3);
    const int c0 = w, c1 = w + 4;
    const unsigned short* gA0 = A + (size_t)(bm + c0 * 16 + srow) * K + skch * 8;
    const unsigned short* gA1 = A + (size_t)(bm + c1 * 16 + srow) * K + skch * 8;
    const unsigned short* gB0 = B + (size_t)(bn + c0 * 16 + srow) * K + skch * 8;
    const unsigned short* gB1 = B + (size_t)(bn + c1 * 16 + srow) * K + skch * 8;
    char* lA0 = (char*)Alds + c0 * 1024;
    char* lA1 = (char*)Alds + c1 * 1024;
    char* lB0 = (char*)Blds + c0 * 1024;
    char* lB1 = (char*)Blds + c1 * 1024;

    const int kbyte = (((lane >> 4) ^ ((lane >> 1) & 3)) << 4);
    const int rA = wr * 64 + (lane & 15);
    const int rB = wc * 64 + (lane & 15);

    f32x4 acc[4][4] = {};

    for (int kt = 0; kt < K; kt += 32) {
        async_cp16(gA0, lA0);
        async_cp16(gA1, lA1);
        async_cp16(gB0, lB0);
        async_cp16(gB1, lB1);
        gA0 += 32; gA1 += 32; gB0 += 32; gB1 += 32;
        __syncthreads();

        bf16x8 a[4], b[4];
#pragma unroll
        for (int i = 0; i < 4; ++i) {
            a[i] = *(const bf16x8*)((const char*)Alds + (rA + i * 16) * 64 + kbyte);
            b[i] = *(const bf16x8*)((const char*)Blds + (rB + i * 16) * 64 + kbyte);
        }
#pragma unroll
        for (int i = 0; i < 4; ++i)
#pragma unroll
            for (int j = 0; j < 4; ++j)
                acc[i][j] = __builtin_amdgcn_mfma_f32_16x16x32_bf16(
                    a[i], b[j], acc[i][j], 0, 0, 0);
        __syncthreads();
    }

    const int orow = (lane >> 4) * 4;
    const int ocol = lane & 15;
#pragma unroll
    for (int i = 0; i < 4; ++i)
#pragma unroll
        for (int j = 0; j < 4; ++j) {
            const size_t base =
                (size_t)(bm + wr * 64 + i * 16 + orow) * N + (bn + wc * 64 + j * 16 + ocol);
#pragma unroll
            for (int r = 0; r < 4; ++r) {
                if constexpr (BF16_OUT)
                    ((unsigned short*)Cv)[base + (size_t)r * N] = f2bf(acc[i][j][r]);
                else
                    ((float*)Cv)[base + (size_t)r * N] = acc[i][j][r];
            }
        }
}

// ---------------------------------------------------------------------------
// Streaming per-tile top-4: aux[row][tile][4] from scoresb (bf16).
// One wave per row; per 512-col group, 4 parallel 16-lane tournaments.
// Low register pressure by construction (fresh 4-deep list per group).
// ---------------------------------------------------------------------------
__global__ __launch_bounds__(256)
void aux_pass(const unsigned short* __restrict__ scoresb,
              float4* __restrict__ aux) {
    const int tid  = threadIdx.x;
    const int lane = tid & 63;
    const int w    = tid >> 6;
    const int t    = blockIdx.x * 4 + w;
    const unsigned short* srow = scoresb + (size_t)t * NSLOTS;

#pragma unroll
    for (int j = 0; j < 8; ++j) {
        const int c0 = j * 512 + lane * 8;
        const u16x8 s8 = *(const u16x8*)(srow + c0);
        float v0 = -INFINITY, v1 = -INFINITY, v2 = -INFINITY, v3 = -INFINITY;
        int   i0 = 0x7fffffff, i1 = 0x7fffffff, i2 = 0x7fffffff, i3 = 0x7fffffff;
#pragma unroll
        for (int e = 0; e < 8; ++e)
            cand_insert(bf2f(s8[e]), c0 + e, v0, i0, v1, i1, v2, i2, v3, i3);
        // 16-lane butterfly (off<16 keeps traffic within each tile's lane group)
#pragma unroll
        for (int off = 1; off < 16; off <<= 1) {
            float s0 = __shfl_xor(v0, off), s1 = __shfl_xor(v1, off);
            float s2 = __shfl_xor(v2, off), s3 = __shfl_xor(v3, off);
            int   t0 = __shfl_xor(i0, off), t1 = __shfl_xor(i1, off);
            int   t2 = __shfl_xor(i2, off), t3 = __shfl_xor(i3, off);
            cand_insert(s0, t0, v0, i0, v1, i1, v2, i2, v3, i3);
            cand_insert(s1, t1, v0, i0, v1, i1, v2, i2, v3, i3);
            cand_insert(s2, t2, v0, i0, v1, i1, v2, i2, v3, i3);
            cand_insert(s3, t3, v0, i0, v1, i1, v2, i2, v3, i3);
        }
        if ((lane & 15) == 0) {
            const int tile = j * 4 + (lane >> 4);
            float4* dst = aux + ((size_t)t * NTILES + tile) * 2;
            float4 o1, o2;
            o1.x = v0; o1.y = __int_as_float(i0); o1.z = v1; o1.w = __int_as_float(i1);
            o2.x = v2; o2.y = __int_as_float(i2); o2.z = v3; o2.w = __int_as_float(i3);
            dst[0] = o1;
            dst[1] = o2;
        }
    }
}

// ---------------------------------------------------------------------------
// Wave-per-row refine: merge aux (32 tiles x top-4) -> thresh -> candidates
// from aux (non-flagged tiles) + stored-score scan (flagged tiles, rare)
// -> EXACT fp32 re-score (identical math to rounds 2-5) -> softmax -> gather.
// ---------------------------------------------------------------------------
__global__ __launch_bounds__(256)
void topk_refine(const float4* __restrict__ aux,
                 const unsigned short* __restrict__ scoresb,
                 const float* __restrict__ x,
                 const float* __restrict__ KW,
                 const unsigned short* __restrict__ svb,
                 unsigned short* __restrict__ retr) {
    const int tid  = threadIdx.x;
    const int lane = tid & 63;
    const int w    = tid >> 6;
    const int t    = blockIdx.x * 4 + w;

    // x row into registers early (independent of everything below)
    const float* xrow = x + (size_t)t * D_DIM + lane * 4;
    float4 xv[8];
#pragma unroll
    for (int i = 0; i < 8; ++i) xv[i] = *(const float4*)(xrow + 256 * i);

    __shared__ int          cand[4][CAND_MAX];
    __shared__ int          ncand[4];
    __shared__ unsigned int flags[4];
    if (lane == 0) { ncand[w] = 0; flags[w] = 0; }
    __syncthreads();

    // --- merge 128 aux entries (lane holds 2: one float4)
    const float4 e2 = aux[(size_t)t * 64 + lane];
    float v0 = -INFINITY, v1 = -INFINITY, v2 = -INFINITY, v3 = -INFINITY;
    int   i0 = 0x7fffffff, i1 = 0x7fffffff, i2 = 0x7fffffff, i3 = 0x7fffffff;
    cand_insert(e2.x, __float_as_int(e2.y), v0, i0, v1, i1, v2, i2, v3, i3);
    cand_insert(e2.z, __float_as_int(e2.w), v0, i0, v1, i1, v2, i2, v3, i3);
#pragma unroll
    for (int off = 1; off < 64; off <<= 1) {
        float s0 = __shfl_xor(v0, off), s1 = __shfl_xor(v1, off);
        float s2 = __shfl_xor(v2, off), s3 = __shfl_xor(v3, off);
        int   j0 = __shfl_xor(i0, off), j1 = __shfl_xor(i1, off);
        int   j2 = __shfl_xor(i2, off), j3 = __shfl_xor(i3, off);
        cand_insert(s0, j0, v0, i0, v1, i1, v2, i2, v3, i3);
        cand_insert(s1, j1, v0, i0, v1, i1, v2, i2, v3, i3);
        cand_insert(s2, j2, v0, i0, v1, i1, v2, i2, v3, i3);
        cand_insert(s3, j3, v0, i0, v1, i1, v2, i2, v3, i3);
    }
    const float thresh = v3 - MARGIN;

    // --- flag tiles whose 4th entry >= thresh (could hide candidates)
    if ((lane & 1) && e2.z >= thresh)
        atomicOr(&flags[w], 1u << (lane >> 1));
    __syncthreads();
    const unsigned int fl = flags[w];

    // --- collect candidates from aux (non-flagged tiles only)
    const int mytile = lane >> 1;
    if (!((fl >> mytile) & 1u)) {
        if (e2.x >= thresh) {
            int p = atomicAdd(&ncand[w], 1);
            if (p < CAND_MAX) cand[w][p] = __float_as_int(e2.y);
        }
        if (e2.z >= thresh) {
            int p = atomicAdd(&ncand[w], 1);
            if (p < CAND_MAX) cand[w][p] = __float_as_int(e2.w);
        }
    }
    // --- flagged tiles: scan stored bf16 scores (rare)
    unsigned int fscan = fl;
    while (fscan) {
        const int tb = __ffs(fscan) - 1;
        fscan &= fscan - 1;
        const unsigned short* srow =
            scoresb + (size_t)t * NSLOTS + tb * 128 + lane * 2;
        const unsigned short s0 = srow[0], s1 = srow[1];
        if (bf2f(s0) >= thresh) {
            int p = atomicAdd(&ncand[w], 1);
            if (p < CAND_MAX) cand[w][p] = tb * 128 + lane * 2;
        }
        if (bf2f(s1) >= thresh) {
            int p = atomicAdd(&ncand[w], 1);
            if (p < CAND_MAX) cand[w][p] = tb * 128 + lane * 2 + 1;
        }
    }
    __syncthreads();
    const int nc = min(ncand[w], CAND_MAX);

    // --- exact fp32 re-score (IDENTICAL math to round-3 validated path)
    float r0 = -INFINITY, r1 = -INFINITY, r2 = -INFINITY, r3 = -INFINITY;
    int   q0 = 0x7fffffff, q1 = 0x7fffffff, q2 = 0x7fffffff, q3 = 0x7fffffff;
    for (int c = 0; c < nc; ++c) {
        const int slot = cand[w][c];
        const float* kr = KW + (size_t)slot * D_DIM + lane * 4;
        float p = 0.0f;
#pragma unroll
        for (int i = 0; i < 8; ++i) {
            const float4 k4 = *(const float4*)(kr + 256 * i);
            p = fmaf(xv[i].x, k4.x, p);
            p = fmaf(xv[i].y, k4.y, p);
            p = fmaf(xv[i].z, k4.z, p);
            p = fmaf(xv[i].w, k4.w, p);
        }
#pragma unroll
        for (int off = 1; off < 64; off <<= 1) p += __shfl_xor(p, off);
        cand_insert(p, slot, r0, q0, r1, q1, r2, q2, r3, q3);
    }

    // --- softmax over scaled top-4 (r0 is max)
    const float e1s = expf(SCALE * (r1 - r0));
    const float e2s = expf(SCALE * (r2 - r0));
    const float e3s = expf(SCALE * (r3 - r0));
    const float inv = 1.0f / (1.0f + e1s + e2s + e3s);
    const float w0s = inv, w1s = e1s * inv, w2s = e2s * inv, w3s = e3s * inv;

    // --- gather bf16 SV rows, weighted sum, write retr (bf16)
    const unsigned short* p0 = svb + (size_t)q0 * D_DIM;
    const unsigned short* p1 = svb + (size_t)q1 * D_DIM;
    const unsigned short* p2 = svb + (size_t)q2 * D_DIM;
    const unsigned short* p3 = svb + (size_t)q3 * D_DIM;
    unsigned short* orow = retr + (size_t)t * D_DIM;
#pragma unroll
    for (int i = 0; i < 4; ++i) {
        const int d0 = lane * 8 + 512 * i;
        u16x8 a0 = *(const u16x8*)(p0 + d0);
        u16x8 a1 = *(const u16x8*)(p1 + d0);
        u16x8 a2 = *(const u16x8*)(p2 + d0);
        u16x8 a3 = *(const u16x8*)(p3 + d0);
        u16x8 o;
#pragma unroll
        for (int e = 0; e < 8; ++e) {
            float s = w0s * bf2f(a0[e]) + w1s * bf2f(a1[e]) +
                      w2s * bf2f(a2[e]) + w3s * bf2f(a3[e]);
            o[e] = f2bf(s);
        }
        *(u16x8*)(orow + d0) = o;
    }
}

// ---------------------------------------------------------------------------
extern "C" void kernel_launch(void* const* d_in, const int* in_sizes, int n_in,
                              void* d_out, int out_size, void* d_ws, size_t ws_size,
                              hipStream_t stream) {
    const float* x    = (const float*)d_in[0];
    const float* sk   = (const float*)d_in[1];
    const float* sv   = (const float*)d_in[2];
    const float* wq   = (const float*)d_in[3];
    const float* wout = (const float*)d_in[4];

    // workspace layout (293.6 MB; proven ws >= 402 MB)
    char* base = (char*)d_ws;
    float*          kwpart  = (float*)base;                       // 4 x 33.55 MB (then reused)
    unsigned short* scoresb = (unsigned short*)base;              // 134.2 MB (after reduce)
    float*          KW      = (float*)(base + 134217728);         //  33.55 MB
    unsigned short* kwb     = (unsigned short*)(base + 167772160);//  16.78 MB
    unsigned short* woutb   = (unsigned short*)(base + 184549376);//   8.39 MB
    unsigned short* xb      = (unsigned short*)(base + 192937984);//  67.11 MB (reused as retr)
    unsigned short* svb     = (unsigned short*)(base + 260046848);//  16.78 MB
    float4*         aux     = (float4*)(base + 276824064);        //  16.78 MB

    const dim3 blk(256);

    // KW partials: SK @ Wq, K split 4 ways
    gemm_ab_f32_ksplit<<<dim3(D_DIM / 128, NSLOTS / 128, KSPLIT), blk, 0, stream>>>(
        sk, wq, kwpart, NSLOTS, D_DIM, D_DIM);

    // KW = sum(partials); kwb = bf16(KW)
    reduce_kw<<<dim3((NSLOTS * (size_t)D_DIM) / 1024), blk, 0, stream>>>(
        kwpart, KW, kwb);

    // bf16 copies
    cvt_f32_bf16<<<dim3((BT_DIM * (size_t)D_DIM) / 2048), blk, 0, stream>>>(x, xb);
    cvt_f32_bf16<<<dim3((D_DIM * (size_t)D_DIM) / 2048), blk, 0, stream>>>(wout, woutb);
    cvt_f32_bf16<<<dim3((NSLOTS * (size_t)D_DIM) / 2048), blk, 0, stream>>>(sv, svb);

    // approx scores (bf16 out) = xb @ kwb^T  [overwrites kwpart region]
    gemm_bf16_abt<true><<<dim3(NSLOTS / 128, BT_DIM / 128), blk, 0, stream>>>(
        xb, kwb, scoresb, BT_DIM, NSLOTS, D_DIM);

    // per-tile top-4 summary (streaming, spill-free)
    aux_pass<<<dim3(BT_DIM / 4), blk, 0, stream>>>(scoresb, aux);

    // exact top-4 via aux + margin-refine; writes retrieved (bf16) over xb
    topk_refine<<<dim3(BT_DIM / 4), blk, 0, stream>>>(
        aux, scoresb, x, KW, svb, xb);

    // out = retrieved @ Wout^T  (fp32 out)
    gemm_bf16_abt<false><<<dim3(D_DIM / 128, BT_DIM / 128), blk, 0, stream>>>(
        xb, woutb, (float*)d_out, BT_DIM, D_DIM, D_DIM);
}

// Round 7
// 1283.813 us; speedup vs baseline: 5.7125x; 2.0220x over previous
//
#include <hip/hip_runtime.h>
#include <math.h>

#define D_DIM    2048
#define BT_DIM   16384   // B*T
#define NSLOTS   4096
#define NTILES   32      // NSLOTS / 128
#define SCALE    0.02209708691207961f  // 1/sqrt(2048)
#define MARGIN   0.02f
#define CAND_MAX 16
#define KSPLIT   4

typedef __attribute__((ext_vector_type(8))) short bf16x8;
typedef __attribute__((ext_vector_type(4))) float f32x4;
typedef __attribute__((ext_vector_type(8))) unsigned short u16x8;
typedef __attribute__((ext_vector_type(4))) unsigned short u16x4;

__device__ __forceinline__ unsigned short f2bf(float f) {
    unsigned int u = __float_as_uint(f);
    return (unsigned short)((u + 0x7fffu + ((u >> 16) & 1u)) >> 16);
}
__device__ __forceinline__ float bf2f(unsigned short s) {
    return __uint_as_float(((unsigned int)s) << 16);
}

__device__ __forceinline__ void async_cp16(const void* g, void* l) {
    __builtin_amdgcn_global_load_lds(
        (const __attribute__((address_space(1))) void*)g,
        (__attribute__((address_space(3))) void*)l, 16, 0, 0);
}

// ---------------------------------------------------------------------------
// top-4 helpers (jax semantics: val desc, idx asc) -- used in refine merge
// ---------------------------------------------------------------------------
__device__ __forceinline__ bool cand_better(float v, int i, float v2, int i2) {
    return (v > v2) || (v == v2 && i < i2);
}

__device__ __forceinline__ void cand_insert(float v, int idx,
                                            float& v0, int& i0, float& v1, int& i1,
                                            float& v2, int& i2, float& v3, int& i3) {
    if (cand_better(v, idx, v3, i3)) {
        if (cand_better(v, idx, v0, i0)) {
            v3 = v2; i3 = i2; v2 = v1; i2 = i1; v1 = v0; i1 = i0; v0 = v; i0 = idx;
        } else if (cand_better(v, idx, v1, i1)) {
            v3 = v2; i3 = i2; v2 = v1; i2 = i1; v1 = v; i1 = idx;
        } else if (cand_better(v, idx, v2, i2)) {
            v3 = v2; i3 = i2; v2 = v; i2 = idx;
        } else {
            v3 = v; i3 = idx;
        }
    }
}

// ---------------------------------------------------------------------------
// fp32: Cpart[z] = A[M,Kc] @ B[Kc,N] for K-chunk z (K-split for occupancy).
// KNOWN-GOOD math (rounds 2-6): per-16-step local accumulator feeds the
// exact-refine path -- do not change accumulation order.
// ---------------------------------------------------------------------------
__global__ __launch_bounds__(256)
void gemm_ab_f32_ksplit(const float* __restrict__ A, const float* __restrict__ B,
                        float* __restrict__ Cpart, int M, int N, int K) {
    __shared__ float As[16][128];   // [k][m]
    __shared__ float Bs[16][128];   // [k][n]

    const int tid = threadIdx.x;
    const int bm  = blockIdx.y * 128;
    const int bn  = blockIdx.x * 128;
    const int kc  = K / KSPLIT;
    const int ks  = blockIdx.z * kc;
    float* C = Cpart + (size_t)blockIdx.z * M * N;
    const int ty  = tid >> 4;
    const int tx  = tid & 15;

    float acc[2][2][4][4];
#pragma unroll
    for (int rb = 0; rb < 2; ++rb)
#pragma unroll
        for (int cb = 0; cb < 2; ++cb)
#pragma unroll
            for (int i = 0; i < 4; ++i)
#pragma unroll
                for (int j = 0; j < 4; ++j) acc[rb][cb][i][j] = 0.0f;

    for (int k0 = ks; k0 < ks + kc; k0 += 16) {
#pragma unroll
        for (int half = 0; half < 2; ++half) {
            const int p = tid + half * 256;
            const int rowA = p >> 2;
            const int kkA  = (p & 3) << 2;
            float4 a4 = *(const float4*)(A + (size_t)(bm + rowA) * K + (k0 + kkA));
            As[kkA + 0][rowA] = a4.x;
            As[kkA + 1][rowA] = a4.y;
            As[kkA + 2][rowA] = a4.z;
            As[kkA + 3][rowA] = a4.w;
            const int kB = p >> 5;
            const int n4 = (p & 31) << 2;
            float4 b4 = *(const float4*)(B + (size_t)(k0 + kB) * N + (bn + n4));
            *(float4*)&Bs[kB][n4] = b4;
        }
        __syncthreads();

        float lacc[2][2][4][4];
#pragma unroll
        for (int rb = 0; rb < 2; ++rb)
#pragma unroll
            for (int cb = 0; cb < 2; ++cb)
#pragma unroll
                for (int i = 0; i < 4; ++i)
#pragma unroll
                    for (int j = 0; j < 4; ++j) lacc[rb][cb][i][j] = 0.0f;

#pragma unroll
        for (int k = 0; k < 16; ++k) {
            float a[2][4], b[2][4];
#pragma unroll
            for (int h = 0; h < 2; ++h) {
                *(float4*)a[h] = *(const float4*)&As[k][h * 64 + ty * 4];
                *(float4*)b[h] = *(const float4*)&Bs[k][h * 64 + tx * 4];
            }
#pragma unroll
            for (int rb = 0; rb < 2; ++rb)
#pragma unroll
                for (int cb = 0; cb < 2; ++cb)
#pragma unroll
                    for (int i = 0; i < 4; ++i)
#pragma unroll
                        for (int j = 0; j < 4; ++j)
                            lacc[rb][cb][i][j] =
                                fmaf(a[rb][i], b[cb][j], lacc[rb][cb][i][j]);
        }
#pragma unroll
        for (int rb = 0; rb < 2; ++rb)
#pragma unroll
            for (int cb = 0; cb < 2; ++cb)
#pragma unroll
                for (int i = 0; i < 4; ++i)
#pragma unroll
                    for (int j = 0; j < 4; ++j)
                        acc[rb][cb][i][j] += lacc[rb][cb][i][j];
        __syncthreads();
    }

#pragma unroll
    for (int rb = 0; rb < 2; ++rb)
#pragma unroll
        for (int i = 0; i < 4; ++i) {
            const size_t r = (size_t)(bm + rb * 64 + ty * 4 + i);
#pragma unroll
            for (int cb = 0; cb < 2; ++cb) {
                float4 o;
                o.x = acc[rb][cb][i][0];
                o.y = acc[rb][cb][i][1];
                o.z = acc[rb][cb][i][2];
                o.w = acc[rb][cb][i][3];
                *(float4*)(C + r * N + (bn + cb * 64 + tx * 4)) = o;
            }
        }
}

// ---------------------------------------------------------------------------
// KW = sum of 4 K-chunk partials (deterministic); also emit kwb = bf16(KW).
// ---------------------------------------------------------------------------
__global__ __launch_bounds__(256)
void reduce_kw(const float* __restrict__ part, float* __restrict__ KW,
               unsigned short* __restrict__ kwb) {
    const size_t i = ((size_t)blockIdx.x * 256 + threadIdx.x) * 4;
    const size_t stride = (size_t)NSLOTS * D_DIM;
    float4 s0 = *(const float4*)(part + i);
    float4 s1 = *(const float4*)(part + i + stride);
    float4 s2 = *(const float4*)(part + i + 2 * stride);
    float4 s3 = *(const float4*)(part + i + 3 * stride);
    float4 o;
    o.x = (s0.x + s1.x) + (s2.x + s3.x);
    o.y = (s0.y + s1.y) + (s2.y + s3.y);
    o.z = (s0.z + s1.z) + (s2.z + s3.z);
    o.w = (s0.w + s1.w) + (s2.w + s3.w);
    *(float4*)(KW + i) = o;
    u16x4 b;
    b[0] = f2bf(o.x); b[1] = f2bf(o.y); b[2] = f2bf(o.z); b[3] = f2bf(o.w);
    *(u16x4*)(kwb + i) = b;
}

// ---------------------------------------------------------------------------
// fp32 -> bf16 elementwise (8 elems/thread), exact grid
// ---------------------------------------------------------------------------
__global__ __launch_bounds__(256)
void cvt_f32_bf16(const float* __restrict__ in, unsigned short* __restrict__ out) {
    const size_t i = ((size_t)blockIdx.x * 256 + threadIdx.x) * 8;
    float4 a = *(const float4*)(in + i);
    float4 b = *(const float4*)(in + i + 4);
    u16x8 o;
    o[0] = f2bf(a.x); o[1] = f2bf(a.y); o[2] = f2bf(a.z); o[3] = f2bf(a.w);
    o[4] = f2bf(b.x); o[5] = f2bf(b.y); o[6] = f2bf(b.z); o[7] = f2bf(b.w);
    *(u16x8*)(out + i) = o;
}

// ---------------------------------------------------------------------------
// bf16 MFMA GEMM: C[M,N] = A[M,K] @ B[N,K]^T; C fp32 or bf16 (template).
// m97 structure, PURE (r5 lesson: no heavy epilogue fusion).
// ---------------------------------------------------------------------------
template <bool BF16_OUT>
__global__ __launch_bounds__(256)
void gemm_bf16_abt(const unsigned short* __restrict__ A,
                   const unsigned short* __restrict__ B,
                   void* __restrict__ Cv, int M, int N, int K) {
    __shared__ __align__(16) unsigned short Alds[128 * 32];
    __shared__ __align__(16) unsigned short Blds[128 * 32];

    const int tid  = threadIdx.x;
    const int lane = tid & 63;
    const int w    = tid >> 6;
    const int wr   = w >> 1, wc = w & 1;
    const int bm   = blockIdx.y * 128;
    const int bn   = blockIdx.x * 128;

    const int srow = lane >> 2;
    const int skch = (lane & 3) ^ ((lane >> 3) & 3);
    const int c0 = w, c1 = w + 4;
    const unsigned short* gA0 = A + (size_t)(bm + c0 * 16 + srow) * K + skch * 8;
    const unsigned short* gA1 = A + (size_t)(bm + c1 * 16 + srow) * K + skch * 8;
    const unsigned short* gB0 = B + (size_t)(bn + c0 * 16 + srow) * K + skch * 8;
    const unsigned short* gB1 = B + (size_t)(bn + c1 * 16 + srow) * K + skch * 8;
    char* lA0 = (char*)Alds + c0 * 1024;
    char* lA1 = (char*)Alds + c1 * 1024;
    char* lB0 = (char*)Blds + c0 * 1024;
    char* lB1 = (char*)Blds + c1 * 1024;

    const int kbyte = (((lane >> 4) ^ ((lane >> 1) & 3)) << 4);
    const int rA = wr * 64 + (lane & 15);
    const int rB = wc * 64 + (lane & 15);

    f32x4 acc[4][4] = {};

    for (int kt = 0; kt < K; kt += 32) {
        async_cp16(gA0, lA0);
        async_cp16(gA1, lA1);
        async_cp16(gB0, lB0);
        async_cp16(gB1, lB1);
        gA0 += 32; gA1 += 32; gB0 += 32; gB1 += 32;
        __syncthreads();

        bf16x8 a[4], b[4];
#pragma unroll
        for (int i = 0; i < 4; ++i) {
            a[i] = *(const bf16x8*)((const char*)Alds + (rA + i * 16) * 64 + kbyte);
            b[i] = *(const bf16x8*)((const char*)Blds + (rB + i * 16) * 64 + kbyte);
        }
#pragma unroll
        for (int i = 0; i < 4; ++i)
#pragma unroll
            for (int j = 0; j < 4; ++j)
                acc[i][j] = __builtin_amdgcn_mfma_f32_16x16x32_bf16(
                    a[i], b[j], acc[i][j], 0, 0, 0);
        __syncthreads();
    }

    const int orow = (lane >> 4) * 4;
    const int ocol = lane & 15;
#pragma unroll
    for (int i = 0; i < 4; ++i)
#pragma unroll
        for (int j = 0; j < 4; ++j) {
            const size_t base =
                (size_t)(bm + wr * 64 + i * 16 + orow) * N + (bn + wc * 64 + j * 16 + ocol);
#pragma unroll
            for (int r = 0; r < 4; ++r) {
                if constexpr (BF16_OUT)
                    ((unsigned short*)Cv)[base + (size_t)r * N] = f2bf(acc[i][j][r]);
                else
                    ((float*)Cv)[base + (size_t)r * N] = acc[i][j][r];
            }
        }
}

// ---------------------------------------------------------------------------
// Streaming per-tile top-4 -- BRANCHLESS (round-6 lesson: insertion-sort
// top-k is serial-dependency-bound on SIMT; 1270us at VALUBusy=7%).
// Pack (bf16 value, idx) order-isomorphically into u32:
//   key = ord16(v) << 12 | (4095 - idx);  ord16(b) = b ^ (sign ? 0xffff : 0x8000)
// Top-4 = 4 passes of {8-elem v_max_u32 tree -> 16-lane shfl-max butterfly
// -> mask winner}. All single-instr max, no branches.
// ---------------------------------------------------------------------------
__global__ __launch_bounds__(256)
void aux_pass(const unsigned short* __restrict__ scoresb,
              float4* __restrict__ aux) {
    const int tid  = threadIdx.x;
    const int lane = tid & 63;
    const int w    = tid >> 6;
    const int t    = blockIdx.x * 4 + w;
    const unsigned short* srow = scoresb + (size_t)t * NSLOTS;

#pragma unroll
    for (int j = 0; j < 8; ++j) {
        const int c0 = j * 512 + lane * 8;   // tile = j*4 + (lane>>4)
        const u16x8 s8 = *(const u16x8*)(srow + c0);
        unsigned int k[8];
#pragma unroll
        for (int e = 0; e < 8; ++e) {
            const unsigned int b   = (unsigned int)s8[e] & 0xffffu;
            const unsigned int ord = b ^ ((b & 0x8000u) ? 0xffffu : 0x8000u);
            k[e] = (ord << 12) | (4095u - (unsigned int)(c0 + e));
        }
        unsigned int win[4];
#pragma unroll
        for (int p = 0; p < 4; ++p) {
            unsigned int m01 = max(k[0], k[1]), m23 = max(k[2], k[3]);
            unsigned int m45 = max(k[4], k[5]), m67 = max(k[6], k[7]);
            unsigned int m = max(max(m01, m23), max(m45, m67));
#pragma unroll
            for (int off = 1; off < 16; off <<= 1)
                m = max(m, (unsigned int)__shfl_xor((int)m, off));
            win[p] = m;
#pragma unroll
            for (int e = 0; e < 8; ++e) k[e] = (k[e] == m) ? 0u : k[e];
        }
        if ((lane & 15) == 0) {
            float vv[4]; int id[4];
#pragma unroll
            for (int p = 0; p < 4; ++p) {
                const unsigned int ord = win[p] >> 12;
                const unsigned int b =
                    (ord & 0x8000u) ? (ord ^ 0x8000u) : (~ord & 0xffffu);
                vv[p] = bf2f((unsigned short)b);
                id[p] = 4095 - (int)(win[p] & 0xfffu);
            }
            const int tile = j * 4 + (lane >> 4);
            float4* dst = aux + ((size_t)t * NTILES + tile) * 2;
            float4 o1, o2;
            o1.x = vv[0]; o1.y = __int_as_float(id[0]);
            o1.z = vv[1]; o1.w = __int_as_float(id[1]);
            o2.x = vv[2]; o2.y = __int_as_float(id[2]);
            o2.z = vv[3]; o2.w = __int_as_float(id[3]);
            dst[0] = o1;
            dst[1] = o2;
        }
    }
}

// ---------------------------------------------------------------------------
// Wave-per-row refine: merge aux (32 tiles x top-4) -> thresh -> candidates
// from aux (non-flagged tiles) + stored-score scan (flagged tiles, rare)
// -> EXACT fp32 re-score (identical math to rounds 2-6) -> softmax -> gather.
// ---------------------------------------------------------------------------
__global__ __launch_bounds__(256)
void topk_refine(const float4* __restrict__ aux,
                 const unsigned short* __restrict__ scoresb,
                 const float* __restrict__ x,
                 const float* __restrict__ KW,
                 const unsigned short* __restrict__ svb,
                 unsigned short* __restrict__ retr) {
    const int tid  = threadIdx.x;
    const int lane = tid & 63;
    const int w    = tid >> 6;
    const int t    = blockIdx.x * 4 + w;

    // x row into registers early (independent of everything below)
    const float* xrow = x + (size_t)t * D_DIM + lane * 4;
    float4 xv[8];
#pragma unroll
    for (int i = 0; i < 8; ++i) xv[i] = *(const float4*)(xrow + 256 * i);

    __shared__ int          cand[4][CAND_MAX];
    __shared__ int          ncand[4];
    __shared__ unsigned int flags[4];
    if (lane == 0) { ncand[w] = 0; flags[w] = 0; }
    __syncthreads();

    // --- merge 128 aux entries (lane holds 2: one float4)
    const float4 e2 = aux[(size_t)t * 64 + lane];
    float v0 = -INFINITY, v1 = -INFINITY, v2 = -INFINITY, v3 = -INFINITY;
    int   i0 = 0x7fffffff, i1 = 0x7fffffff, i2 = 0x7fffffff, i3 = 0x7fffffff;
    cand_insert(e2.x, __float_as_int(e2.y), v0, i0, v1, i1, v2, i2, v3, i3);
    cand_insert(e2.z, __float_as_int(e2.w), v0, i0, v1, i1, v2, i2, v3, i3);
#pragma unroll
    for (int off = 1; off < 64; off <<= 1) {
        float s0 = __shfl_xor(v0, off), s1 = __shfl_xor(v1, off);
        float s2 = __shfl_xor(v2, off), s3 = __shfl_xor(v3, off);
        int   j0 = __shfl_xor(i0, off), j1 = __shfl_xor(i1, off);
        int   j2 = __shfl_xor(i2, off), j3 = __shfl_xor(i3, off);
        cand_insert(s0, j0, v0, i0, v1, i1, v2, i2, v3, i3);
        cand_insert(s1, j1, v0, i0, v1, i1, v2, i2, v3, i3);
        cand_insert(s2, j2, v0, i0, v1, i1, v2, i2, v3, i3);
        cand_insert(s3, j3, v0, i0, v1, i1, v2, i2, v3, i3);
    }
    const float thresh = v3 - MARGIN;

    // --- flag tiles whose 4th entry >= thresh (could hide candidates)
    if ((lane & 1) && e2.z >= thresh)
        atomicOr(&flags[w], 1u << (lane >> 1));
    __syncthreads();
    const unsigned int fl = flags[w];

    // --- collect candidates from aux (non-flagged tiles only)
    const int mytile = lane >> 1;
    if (!((fl >> mytile) & 1u)) {
        if (e2.x >= thresh) {
            int p = atomicAdd(&ncand[w], 1);
            if (p < CAND_MAX) cand[w][p] = __float_as_int(e2.y);
        }
        if (e2.z >= thresh) {
            int p = atomicAdd(&ncand[w], 1);
            if (p < CAND_MAX) cand[w][p] = __float_as_int(e2.w);
        }
    }
    // --- flagged tiles: scan stored bf16 scores (rare)
    unsigned int fscan = fl;
    while (fscan) {
        const int tb = __ffs(fscan) - 1;
        fscan &= fscan - 1;
        const unsigned short* srow =
            scoresb + (size_t)t * NSLOTS + tb * 128 + lane * 2;
        const unsigned short s0 = srow[0], s1 = srow[1];
        if (bf2f(s0) >= thresh) {
            int p = atomicAdd(&ncand[w], 1);
            if (p < CAND_MAX) cand[w][p] = tb * 128 + lane * 2;
        }
        if (bf2f(s1) >= thresh) {
            int p = atomicAdd(&ncand[w], 1);
            if (p < CAND_MAX) cand[w][p] = tb * 128 + lane * 2 + 1;
        }
    }
    __syncthreads();
    const int nc = min(ncand[w], CAND_MAX);

    // --- exact fp32 re-score (IDENTICAL math to round-3 validated path)
    float r0 = -INFINITY, r1 = -INFINITY, r2 = -INFINITY, r3 = -INFINITY;
    int   q0 = 0x7fffffff, q1 = 0x7fffffff, q2 = 0x7fffffff, q3 = 0x7fffffff;
    for (int c = 0; c < nc; ++c) {
        const int slot = cand[w][c];
        const float* kr = KW + (size_t)slot * D_DIM + lane * 4;
        float p = 0.0f;
#pragma unroll
        for (int i = 0; i < 8; ++i) {
            const float4 k4 = *(const float4*)(kr + 256 * i);
            p = fmaf(xv[i].x, k4.x, p);
            p = fmaf(xv[i].y, k4.y, p);
            p = fmaf(xv[i].z, k4.z, p);
            p = fmaf(xv[i].w, k4.w, p);
        }
#pragma unroll
        for (int off = 1; off < 64; off <<= 1) p += __shfl_xor(p, off);
        cand_insert(p, slot, r0, q0, r1, q1, r2, q2, r3, q3);
    }

    // --- softmax over scaled top-4 (r0 is max)
    const float e1s = expf(SCALE * (r1 - r0));
    const float e2s = expf(SCALE * (r2 - r0));
    const float e3s = expf(SCALE * (r3 - r0));
    const float inv = 1.0f / (1.0f + e1s + e2s + e3s);
    const float w0s = inv, w1s = e1s * inv, w2s = e2s * inv, w3s = e3s * inv;

    // --- gather bf16 SV rows, weighted sum, write retr (bf16)
    const unsigned short* p0 = svb + (size_t)q0 * D_DIM;
    const unsigned short* p1 = svb + (size_t)q1 * D_DIM;
    const unsigned short* p2 = svb + (size_t)q2 * D_DIM;
    const unsigned short* p3 = svb + (size_t)q3 * D_DIM;
    unsigned short* orow = retr + (size_t)t * D_DIM;
#pragma unroll
    for (int i = 0; i < 4; ++i) {
        const int d0 = lane * 8 + 512 * i;
        u16x8 a0 = *(const u16x8*)(p0 + d0);
        u16x8 a1 = *(const u16x8*)(p1 + d0);
        u16x8 a2 = *(const u16x8*)(p2 + d0);
        u16x8 a3 = *(const u16x8*)(p3 + d0);
        u16x8 o;
#pragma unroll
        for (int e = 0; e < 8; ++e) {
            float s = w0s * bf2f(a0[e]) + w1s * bf2f(a1[e]) +
                      w2s * bf2f(a2[e]) + w3s * bf2f(a3[e]);
            o[e] = f2bf(s);
        }
        *(u16x8*)(orow + d0) = o;
    }
}

// ---------------------------------------------------------------------------
extern "C" void kernel_launch(void* const* d_in, const int* in_sizes, int n_in,
                              void* d_out, int out_size, void* d_ws, size_t ws_size,
                              hipStream_t stream) {
    const float* x    = (const float*)d_in[0];
    const float* sk   = (const float*)d_in[1];
    const float* sv   = (const float*)d_in[2];
    const float* wq   = (const float*)d_in[3];
    const float* wout = (const float*)d_in[4];

    // workspace layout (293.6 MB; proven ws >= 402 MB)
    char* base = (char*)d_ws;
    float*          kwpart  = (float*)base;                       // 4 x 33.55 MB (then reused)
    unsigned short* scoresb = (unsigned short*)base;              // 134.2 MB (after reduce)
    float*          KW      = (float*)(base + 134217728);         //  33.55 MB
    unsigned short* kwb     = (unsigned short*)(base + 167772160);//  16.78 MB
    unsigned short* woutb   = (unsigned short*)(base + 184549376);//   8.39 MB
    unsigned short* xb      = (unsigned short*)(base + 192937984);//  67.11 MB (reused as retr)
    unsigned short* svb     = (unsigned short*)(base + 260046848);//  16.78 MB
    float4*         aux     = (float4*)(base + 276824064);        //  16.78 MB

    const dim3 blk(256);

    // KW partials: SK @ Wq, K split 4 ways
    gemm_ab_f32_ksplit<<<dim3(D_DIM / 128, NSLOTS / 128, KSPLIT), blk, 0, stream>>>(
        sk, wq, kwpart, NSLOTS, D_DIM, D_DIM);

    // KW = sum(partials); kwb = bf16(KW)
    reduce_kw<<<dim3((NSLOTS * (size_t)D_DIM) / 1024), blk, 0, stream>>>(
        kwpart, KW, kwb);

    // bf16 copies
    cvt_f32_bf16<<<dim3((BT_DIM * (size_t)D_DIM) / 2048), blk, 0, stream>>>(x, xb);
    cvt_f32_bf16<<<dim3((D_DIM * (size_t)D_DIM) / 2048), blk, 0, stream>>>(wout, woutb);
    cvt_f32_bf16<<<dim3((NSLOTS * (size_t)D_DIM) / 2048), blk, 0, stream>>>(sv, svb);

    // approx scores (bf16 out) = xb @ kwb^T  [overwrites kwpart region]
    gemm_bf16_abt<true><<<dim3(NSLOTS / 128, BT_DIM / 128), blk, 0, stream>>>(
        xb, kwb, scoresb, BT_DIM, NSLOTS, D_DIM);

    // per-tile top-4 summary (branchless packed-key argmax)
    aux_pass<<<dim3(BT_DIM / 4), blk, 0, stream>>>(scoresb, aux);

    // exact top-4 via aux + margin-refine; writes retrieved (bf16) over xb
    topk_refine<<<dim3(BT_DIM / 4), blk, 0, stream>>>(
        aux, scoresb, x, KW, svb, xb);

    // out = retrieved @ Wout^T  (fp32 out)
    gemm_bf16_abt<false><<<dim3(D_DIM / 128, BT_DIM / 128), blk, 0, stream>>>(
        xb, woutb, (float*)d_out, BT_DIM, D_DIM, D_DIM);
}